// Round 7
// baseline (318.380 us; speedup 1.0000x reference)
//
#include <hip/hip_runtime.h>
#include <hip/hip_bf16.h>

typedef short v8s __attribute__((ext_vector_type(8)));
typedef float v4f __attribute__((ext_vector_type(4)));

#define MFMA16(a, b, c) __builtin_amdgcn_mfma_f32_16x16x32_bf16((a), (b), (c), 0, 0, 0)

typedef __attribute__((address_space(1))) const void g_void;
typedef __attribute__((address_space(3))) void lds_void;
#define GLOAD_LDS16(g, l) \
    __builtin_amdgcn_global_load_lds((g_void*)(g), (lds_void*)(l), 16, 0, 0)

constexpr int Bsz   = 128;
constexpr int Lq    = 32;
constexpr int Ld    = 512;
constexpr int H     = 768;
constexpr int D     = 128;
constexpr int QROWS = Bsz * Lq;          // 4096
constexpr int DROWS = Bsz * Ld;          // 65536
constexpr int MTOT  = QROWS + 2 * DROWS; // 135168
constexpr int RPB   = 16;                // rows per block (full-row staging)
constexpr int LROWF = 772;               // padded LDS row stride (f32): 768+4
static_assert(QROWS % RPB == 0 && DROWS % RPB == 0, "block never spans sources");

// f32 -> bf16 bits, round-to-nearest-even
static __device__ __forceinline__ unsigned short f2b(float f) {
    unsigned int u = __builtin_bit_cast(unsigned int, f);
    unsigned int r = u + 0x7FFFu + ((u >> 16) & 1u);
    return (unsigned short)(r >> 16);
}

// ---------------------------------------------------------------------------
// Kernel 0: BW probe — pure float4 grid-stride read of pd_hidden + nd_hidden
// (403 MB). Loads kept live via asm volatile; no stores. Measures the true
// achievable HBM read BW for these tensors in this harness.
// ---------------------------------------------------------------------------
__global__ __launch_bounds__(256) void bw_probe_kernel(
    const float4* __restrict__ pdh4, const float4* __restrict__ ndh4)
{
    const long N4 = (long)Bsz * Ld * H / 4;   // 12.58M float4 per tensor
    const long stride = (long)gridDim.x * 256;
    for (long i = (long)blockIdx.x * 256 + threadIdx.x; i < N4; i += stride) {
        float4 a = pdh4[i];
        float4 b = ndh4[i];
        asm volatile("" :: "v"(a.x), "v"(a.y), "v"(a.z), "v"(a.w));
        asm volatile("" :: "v"(b.x), "v"(b.y), "v"(b.z), "v"(b.w));
    }
}

// ---------------------------------------------------------------------------
// Kernel 1: Wt[d][h] = bf16(W[h][d])
// ---------------------------------------------------------------------------
__global__ void prep_w_kernel(const float* __restrict__ W,
                              unsigned short* __restrict__ Wt) {
    int idx = blockIdx.x * 256 + threadIdx.x;
    if (idx < H * D) {
        int d = idx / H, h = idx % H;
        Wt[idx] = f2b(W[h * D + d]);
    }
}

// ---------------------------------------------------------------------------
// Kernel 2: projection, FULL-ROW streaming.
//   Block = 16 rows x full H. Stage: each row as 3 contiguous 1 KB
//   global_load_lds bursts (DRAM-page friendly: each 3 KB row read once,
//   sequentially). LDS row stride padded +16 B -> uniform bank spread.
//   One barrier after stage; K-loop entirely from LDS, no barriers.
//   Pipelining across 3 independent blocks/CU (50 KB LDS each).
//   Wave w computes all 16 rows x d-cols [16w,16w+16); cross-wave L2-norm.
// ---------------------------------------------------------------------------
__global__ __launch_bounds__(512, 4) void proj_norm_kernel(
    const float* __restrict__ qh, const float* __restrict__ pdh,
    const float* __restrict__ ndh, const float* __restrict__ bias,
    const int* __restrict__ pdm, const int* __restrict__ ndm,
    const unsigned short* __restrict__ Wt, unsigned short* __restrict__ emb)
{
    __shared__ float Lbuf[RPB * LROWF];   // 49408 B
    __shared__ float ssred[8][RPB];       // cross-wave norm partials

    const int tid  = threadIdx.x;
    const int lane = tid & 63, wave = tid >> 6;   // wave 0..7
    const int l15  = lane & 15, lg = lane >> 4;
    const long row0 = (long)blockIdx.x * RPB;

    const float* src; const int* mask; long srow;
    if (row0 < QROWS)              { src = qh;  srow = row0;                 mask = nullptr; }
    else if (row0 < QROWS + DROWS) { src = pdh; srow = row0 - QROWS;         mask = pdm; }
    else                           { src = ndh; srow = row0 - QROWS - DROWS; mask = ndm; }

    // ---- stage: wave w stages rows 2w, 2w+1; 3 contiguous 1 KB bursts each
    {
        const int r0 = 2 * wave, r1 = 2 * wave + 1;
        const float* g0 = src + (srow + r0) * (long)H + lane * 4;
        const float* g1 = src + (srow + r1) * (long)H + lane * 4;
        float* l0 = &Lbuf[r0 * LROWF];
        float* l1 = &Lbuf[r1 * LROWF];
#pragma unroll
        for (int s = 0; s < 3; ++s) {
            GLOAD_LDS16(g0 + s * 256, l0 + s * 256);
            GLOAD_LDS16(g1 + s * 256, l1 + s * 256);
        }
    }
    __syncthreads();

    // ---- K-loop: 24 tiles, all from LDS; W (bf16, L2-hot) direct to regs
    const unsigned short* wp = Wt + (size_t)(wave * 16 + l15) * H + lg * 8;
    const float* ap = &Lbuf[l15 * LROWF + lg * 8];

    v4f acc = (v4f){0.f, 0.f, 0.f, 0.f};
#pragma unroll 4
    for (int kt = 0; kt < H / 32; ++kt) {
        v8s wb = *(const v8s*)(wp + kt * 32);
        float4 f0 = *(const float4*)(ap + kt * 32);
        float4 f1 = *(const float4*)(ap + kt * 32 + 4);
        v8s a;
        a[0] = (short)f2b(f0.x); a[1] = (short)f2b(f0.y);
        a[2] = (short)f2b(f0.z); a[3] = (short)f2b(f0.w);
        a[4] = (short)f2b(f1.x); a[5] = (short)f2b(f1.y);
        a[6] = (short)f2b(f1.z); a[7] = (short)f2b(f1.w);
        acc = MFMA16(a, wb, acc);
    }

    // ---- epilogue: bias, cross-wave L2-norm, mask, store bf16 ----
    const float bvv = bias[wave * 16 + l15];
    float ss[4];
#pragma unroll
    for (int q = 0; q < 4; ++q) {
        float v = acc[q] + bvv;
        acc[q] = v;
        ss[q] = v * v;
    }
#pragma unroll
    for (int off = 1; off < 16; off <<= 1)
#pragma unroll
        for (int q = 0; q < 4; ++q)
            ss[q] += __shfl_xor(ss[q], off);

    if (l15 == 0) {
#pragma unroll
        for (int q = 0; q < 4; ++q)
            ssred[wave][lg * 4 + q] = ss[q];
    }
    __syncthreads();

#pragma unroll
    for (int q = 0; q < 4; ++q) {
        const int row = lg * 4 + q;
        float t = 0.f;
#pragma unroll
        for (int w = 0; w < 8; ++w) t += ssred[w][row];
        float s = 1.0f / fmaxf(sqrtf(t), 1e-12f);
        if (mask) s *= (float)mask[srow + row];
        emb[(size_t)(row0 + row) * D + wave * 16 + l15] = f2b(acc[q] * s);
    }
}

// ---------------------------------------------------------------------------
// Kernel 3: MaxSim. One block per (batch, side); 4 waves x 128 doc tokens.
// ---------------------------------------------------------------------------
__global__ __launch_bounds__(256) void maxsim_kernel(
    const unsigned short* __restrict__ emb, float* __restrict__ out)
{
    const int blk  = blockIdx.x;       // 0..255
    const int b    = blk >> 1, side = blk & 1;
    const int wave = threadIdx.x >> 6, lane = threadIdx.x & 63;
    const int l15  = lane & 15, lg = lane >> 4;

    const unsigned short* Q  = emb + (size_t)(b * Lq) * D;
    const unsigned short* Dm = emb + (size_t)(QROWS + side * DROWS + b * Ld) * D;

    v4f acc[2][8];
#pragma unroll
    for (int m = 0; m < 2; ++m)
#pragma unroll
        for (int n = 0; n < 8; ++n) acc[m][n] = (v4f){0.f, 0.f, 0.f, 0.f};

    const int tok0 = wave * 128;
#pragma unroll
    for (int kk = 0; kk < 4; ++kk) {
        const int k0 = kk * 32 + lg * 8;
        v8s qa0 = *(const v8s*)(Q + (size_t)(l15) * D + k0);
        v8s qa1 = *(const v8s*)(Q + (size_t)(16 + l15) * D + k0);
#pragma unroll
        for (int n = 0; n < 8; ++n) {
            v8s db = *(const v8s*)(Dm + (size_t)(tok0 + n * 16 + l15) * D + k0);
            acc[0][n] = MFMA16(qa0, db, acc[0][n]);
            acc[1][n] = MFMA16(qa1, db, acc[1][n]);
        }
    }

    float mx[2][4];
#pragma unroll
    for (int m = 0; m < 2; ++m)
#pragma unroll
        for (int r = 0; r < 4; ++r) {
            float v = acc[m][0][r];
#pragma unroll
            for (int n = 1; n < 8; ++n) v = fmaxf(v, acc[m][n][r]);
            mx[m][r] = v;
        }
#pragma unroll
    for (int off = 1; off < 16; off <<= 1) {
#pragma unroll
        for (int m = 0; m < 2; ++m)
#pragma unroll
            for (int r = 0; r < 4; ++r)
                mx[m][r] = fmaxf(mx[m][r], __shfl_xor(mx[m][r], off));
    }

    __shared__ float red[4][32];
    if (l15 == 0) {
#pragma unroll
        for (int m = 0; m < 2; ++m)
#pragma unroll
            for (int r = 0; r < 4; ++r)
                red[wave][m * 16 + lg * 4 + r] = mx[m][r];
    }
    __syncthreads();

    if (threadIdx.x < 32) {
        int q = threadIdx.x;
        float v = fmaxf(fmaxf(red[0][q], red[1][q]), fmaxf(red[2][q], red[3][q]));
#pragma unroll
        for (int off = 1; off < 32; off <<= 1) v += __shfl_xor(v, off);
        if (q == 0) out[blk] = v;
    }
}

// ---------------------------------------------------------------------------
extern "C" void kernel_launch(void* const* d_in, const int* in_sizes, int n_in,
                              void* d_out, int out_size, void* d_ws, size_t ws_size,
                              hipStream_t stream)
{
    const float* qh   = (const float*)d_in[0];
    const float* pdh  = (const float*)d_in[1];
    const float* ndh  = (const float*)d_in[2];
    const float* W    = (const float*)d_in[3];
    const float* bias = (const float*)d_in[4];
    const int*   pdm  = (const int*)d_in[5];
    const int*   ndm  = (const int*)d_in[6];
    float* out = (float*)d_out;

    unsigned short* Wt  = (unsigned short*)d_ws;          // [D][H] bf16, 192 KB
    unsigned short* emb = Wt + (size_t)H * D;             // [MTOT][D] bf16

    bw_probe_kernel<<<2048, 256, 0, stream>>>((const float4*)pdh, (const float4*)ndh);
    prep_w_kernel<<<(H * D + 255) / 256, 256, 0, stream>>>(W, Wt);
    proj_norm_kernel<<<MTOT / RPB, 512, 0, stream>>>(qh, pdh, ndh, bias, pdm, ndm, Wt, emb);
    maxsim_kernel<<<Bsz * 2, 256, 0, stream>>>(emb, out);
}

// Round 9
// 156.514 us; speedup vs baseline: 2.0342x; 2.0342x over previous
//
#include <hip/hip_runtime.h>
#include <hip/hip_bf16.h>

typedef short v8s __attribute__((ext_vector_type(8)));
typedef float v4f __attribute__((ext_vector_type(4)));

#define MFMA16(a, b, c) __builtin_amdgcn_mfma_f32_16x16x32_bf16((a), (b), (c), 0, 0, 0)

constexpr int Bsz   = 128;
constexpr int Lq    = 32;
constexpr int Ld    = 512;
constexpr int H     = 768;
constexpr int D     = 128;
constexpr int QROWS = Bsz * Lq;          // 4096
constexpr int DROWS = Bsz * Ld;          // 65536
constexpr int MTOT  = QROWS + 2 * DROWS; // 135168
constexpr int BM    = 32;                // rows per block
constexpr int BK    = 64;                // K per tile
constexpr int NKT   = H / BK;            // 12 K-tiles
static_assert(QROWS % BM == 0 && DROWS % BM == 0, "block never spans sources");

// f32 -> bf16 bits, round-to-nearest-even
static __device__ __forceinline__ unsigned short f2b(float f) {
    unsigned int u = __builtin_bit_cast(unsigned int, f);
    unsigned int r = u + 0x7FFFu + ((u >> 16) & 1u);
    return (unsigned short)(r >> 16);
}
static __device__ __forceinline__ unsigned int pack2(float a, float b) {
    return (unsigned int)f2b(a) | ((unsigned int)f2b(b) << 16);
}

// ---------------------------------------------------------------------------
// Kernel 1: Wt[d][h] = bf16(W[h][d])
// ---------------------------------------------------------------------------
__global__ void prep_w_kernel(const float* __restrict__ W,
                              unsigned short* __restrict__ Wt) {
    int idx = blockIdx.x * 256 + threadIdx.x;
    if (idx < H * D) {
        int d = idx / H, h = idx % H;
        Wt[idx] = f2b(W[h * D + d]);
    }
}

// ---------------------------------------------------------------------------
// Kernel 2: projection, register-staged, bf16 LDS tiles.
//   256 thr = 4 waves; wave w computes rows [0,32) x cols [32w, 32w+32)
//   (full D=128 covered -- R8's bug was 2x2 wave split covering only 64 cols).
//   Per tile: thread loads 8 f32 (2 float4), converts once to bf16, writes
//   2x uint2 into swizzled LDS tile [32][64] bf16 (4 KB, double-buffered).
//   Swizzle: phys8Bslot = logical ^ ((row&7)<<1); read 16B chunk
//   phys = logical ^ (row&7)  (write/read consistent; uniform banks).
//   Pipeline: A at distance 3 (2-slot reg ring), W at distance 3 (3-slot
//   ring), issue order per iter [A(t+3), W(t+3)] keeps the vmcnt FIFO
//   clean; raw s_barrier + lgkmcnt(0) only -- NO vmcnt(0) in the loop.
// ---------------------------------------------------------------------------
__global__ __launch_bounds__(256, 3) void proj_norm_kernel(
    const float* __restrict__ qh, const float* __restrict__ pdh,
    const float* __restrict__ ndh, const float* __restrict__ bias,
    const int* __restrict__ pdm, const int* __restrict__ ndm,
    const unsigned short* __restrict__ Wt, unsigned short* __restrict__ emb)
{
    __shared__ unsigned short Abuf[2][BM * BK];  // 2 x 4 KB bf16
    __shared__ float ssred[4][BM];

    const int tid  = threadIdx.x;
    const int lane = tid & 63, wave = tid >> 6;   // 4 waves = 4 col groups
    const int l15  = lane & 15, lg = lane >> 4;
    const long row0 = (long)blockIdx.x * BM;

    const float* src; const int* mask; long srow;
    if (row0 < QROWS)              { src = qh;  srow = row0;                 mask = nullptr; }
    else if (row0 < QROWS + DROWS) { src = pdh; srow = row0 - QROWS;         mask = pdm; }
    else                           { src = ndh; srow = row0 - QROWS - DROWS; mask = ndm; }

    // global A addressing: row rr = tid>>3 (0..31); cc = tid&7; thread loads
    // float4 at float offsets cc*4 + 32j (j=0,1) of the 64-float tile row.
    const int rr = tid >> 3;
    const int cc = tid & 7;
    const float* gA = src + (srow + rr) * (long)H + cc * 4;

    // Wt fragments: frag (nt,kk) of tile kt at wp + nt*16*H + kt*64 + kk*32
    const unsigned short* wp = Wt + (size_t)(wave * 32 + l15) * H + lg * 8;

    float4 rA[2][2];
    v8s    wt[3][4];
    v4f    acc[2][2];
#pragma unroll
    for (int mt = 0; mt < 2; ++mt)
#pragma unroll
        for (int nt = 0; nt < 2; ++nt) acc[mt][nt] = (v4f){0.f, 0.f, 0.f, 0.f};

    auto issueA = [&](int s, int kt) {
#pragma unroll
        for (int j = 0; j < 2; ++j)
            rA[s][j] = *(const float4*)(gA + kt * BK + j * 32);
    };
    auto issueW = [&](int s, int kt) {
#pragma unroll
        for (int nt = 0; nt < 2; ++nt)
#pragma unroll
            for (int kk = 0; kk < 2; ++kk)
                wt[s][nt * 2 + kk] =
                    *(const v8s*)(wp + (size_t)nt * 16 * H + kt * BK + kk * 32);
    };
    auto convW = [&](int s, int bi) {
#pragma unroll
        for (int j = 0; j < 2; ++j) {
            const int c  = cc + 8 * j;                  // logical 8B slot
            const int sl = c ^ ((rr & 7) << 1);         // swizzled slot
            uint2 u;
            u.x = pack2(rA[s][j].x, rA[s][j].y);
            u.y = pack2(rA[s][j].z, rA[s][j].w);
            *(uint2*)(&Abuf[bi][rr * 64 + sl * 4]) = u;
        }
    };
    auto compute = [&](int bi, int s) {
#pragma unroll
        for (int kk = 0; kk < 2; ++kk) {
            v8s am[2];
#pragma unroll
            for (int mt = 0; mt < 2; ++mt) {
                const int r  = mt * 16 + l15;
                const int ch = (kk * 4 + lg) ^ (r & 7); // swizzled 16B chunk
                am[mt] = *(const v8s*)(&Abuf[bi][r * 64 + ch * 8]);
            }
#pragma unroll
            for (int mt = 0; mt < 2; ++mt)
#pragma unroll
                for (int nt = 0; nt < 2; ++nt)
                    acc[mt][nt] = MFMA16(am[mt], wt[s][nt * 2 + kk], acc[mt][nt]);
        }
    };

    // prologue: G(0), G(1) issued; convert tile0; G(2) issued; barrier
    issueA(0, 0); issueW(0, 0);
    issueA(1, 1); issueW(1, 1);
    convW(0, 0);                       // compiler waits A(0) only (counted)
    issueA(0, 2); issueW(2, 2);
    asm volatile("s_waitcnt lgkmcnt(0)" ::: "memory");
    __builtin_amdgcn_sched_barrier(0);
    __builtin_amdgcn_s_barrier();
    __builtin_amdgcn_sched_barrier(0);

#pragma unroll
    for (int t = 0; t < NKT; ++t) {
        compute(t & 1, t % 3);
        if (t + 1 < NKT) convW((t + 1) & 1, (t + 1) & 1);
        if (t + 3 < NKT) { issueA((t + 3) & 1, t + 3); issueW((t + 3) % 3, t + 3); }
        if (t + 1 < NKT) {
            asm volatile("s_waitcnt lgkmcnt(0)" ::: "memory");
            __builtin_amdgcn_sched_barrier(0);
            __builtin_amdgcn_s_barrier();
            __builtin_amdgcn_sched_barrier(0);
        }
    }

    // ---- epilogue: bias, cross-wave L2-norm (all 4 col groups), store ----
    const float bv0 = bias[wave * 32 + l15];
    const float bv1 = bias[wave * 32 + 16 + l15];

    float ss[2][4];
#pragma unroll
    for (int mt = 0; mt < 2; ++mt)
#pragma unroll
        for (int q = 0; q < 4; ++q) {
            float v0 = acc[mt][0][q] + bv0;
            float v1 = acc[mt][1][q] + bv1;
            acc[mt][0][q] = v0; acc[mt][1][q] = v1;
            ss[mt][q] = v0 * v0 + v1 * v1;
        }
#pragma unroll
    for (int off = 1; off < 16; off <<= 1)
#pragma unroll
        for (int mt = 0; mt < 2; ++mt)
#pragma unroll
            for (int q = 0; q < 4; ++q)
                ss[mt][q] += __shfl_xor(ss[mt][q], off);

    __syncthreads();   // pipeline fully done
    if (l15 == 0) {
#pragma unroll
        for (int mt = 0; mt < 2; ++mt)
#pragma unroll
            for (int q = 0; q < 4; ++q)
                ssred[wave][mt * 16 + lg * 4 + q] = ss[mt][q];
    }
    __syncthreads();

#pragma unroll
    for (int mt = 0; mt < 2; ++mt)
#pragma unroll
        for (int q = 0; q < 4; ++q) {
            const int row = mt * 16 + lg * 4 + q;
            float t = ssred[0][row] + ssred[1][row] + ssred[2][row] + ssred[3][row];
            float s = 1.0f / fmaxf(sqrtf(t), 1e-12f);
            if (mask) s *= (float)mask[srow + row];
            unsigned short* op = emb + (size_t)(row0 + row) * D + wave * 32 + l15;
            op[0]  = f2b(acc[mt][0][q] * s);
            op[16] = f2b(acc[mt][1][q] * s);
        }
}

// ---------------------------------------------------------------------------
// Kernel 3: MaxSim. One block per (batch, side); 4 waves x 128 doc tokens.
// ---------------------------------------------------------------------------
__global__ __launch_bounds__(256) void maxsim_kernel(
    const unsigned short* __restrict__ emb, float* __restrict__ out)
{
    const int blk  = blockIdx.x;       // 0..255
    const int b    = blk >> 1, side = blk & 1;
    const int wave = threadIdx.x >> 6, lane = threadIdx.x & 63;
    const int l15  = lane & 15, lg = lane >> 4;

    const unsigned short* Q  = emb + (size_t)(b * Lq) * D;
    const unsigned short* Dm = emb + (size_t)(QROWS + side * DROWS + b * Ld) * D;

    v4f acc[2][8];
#pragma unroll
    for (int m = 0; m < 2; ++m)
#pragma unroll
        for (int n = 0; n < 8; ++n) acc[m][n] = (v4f){0.f, 0.f, 0.f, 0.f};

    const int tok0 = wave * 128;
#pragma unroll
    for (int kk = 0; kk < 4; ++kk) {
        const int k0 = kk * 32 + lg * 8;
        v8s qa0 = *(const v8s*)(Q + (size_t)(l15) * D + k0);
        v8s qa1 = *(const v8s*)(Q + (size_t)(16 + l15) * D + k0);
#pragma unroll
        for (int n = 0; n < 8; ++n) {
            v8s db = *(const v8s*)(Dm + (size_t)(tok0 + n * 16 + l15) * D + k0);
            acc[0][n] = MFMA16(qa0, db, acc[0][n]);
            acc[1][n] = MFMA16(qa1, db, acc[1][n]);
        }
    }

    float mx[2][4];
#pragma unroll
    for (int m = 0; m < 2; ++m)
#pragma unroll
        for (int r = 0; r < 4; ++r) {
            float v = acc[m][0][r];
#pragma unroll
            for (int n = 1; n < 8; ++n) v = fmaxf(v, acc[m][n][r]);
            mx[m][r] = v;
        }
#pragma unroll
    for (int off = 1; off < 16; off <<= 1) {
#pragma unroll
        for (int m = 0; m < 2; ++m)
#pragma unroll
            for (int r = 0; r < 4; ++r)
                mx[m][r] = fmaxf(mx[m][r], __shfl_xor(mx[m][r], off));
    }

    __shared__ float red[4][32];
    if (l15 == 0) {
#pragma unroll
        for (int m = 0; m < 2; ++m)
#pragma unroll
            for (int r = 0; r < 4; ++r)
                red[wave][m * 16 + lg * 4 + r] = mx[m][r];
    }
    __syncthreads();

    if (threadIdx.x < 32) {
        int q = threadIdx.x;
        float v = fmaxf(fmaxf(red[0][q], red[1][q]), fmaxf(red[2][q], red[3][q]));
#pragma unroll
        for (int off = 1; off < 32; off <<= 1) v += __shfl_xor(v, off);
        if (q == 0) out[blk] = v;
    }
}

// ---------------------------------------------------------------------------
extern "C" void kernel_launch(void* const* d_in, const int* in_sizes, int n_in,
                              void* d_out, int out_size, void* d_ws, size_t ws_size,
                              hipStream_t stream)
{
    const float* qh   = (const float*)d_in[0];
    const float* pdh  = (const float*)d_in[1];
    const float* ndh  = (const float*)d_in[2];
    const float* W    = (const float*)d_in[3];
    const float* bias = (const float*)d_in[4];
    const int*   pdm  = (const int*)d_in[5];
    const int*   ndm  = (const int*)d_in[6];
    float* out = (float*)d_out;

    unsigned short* Wt  = (unsigned short*)d_ws;          // [D][H] bf16, 192 KB
    unsigned short* emb = Wt + (size_t)H * D;             // [MTOT][D] bf16

    prep_w_kernel<<<(H * D + 255) / 256, 256, 0, stream>>>(W, Wt);
    proj_norm_kernel<<<MTOT / BM, 256, 0, stream>>>(qh, pdh, ndh, bias, pdm, ndm, Wt, emb);
    maxsim_kernel<<<Bsz * 2, 256, 0, stream>>>(emb, out);
}

// Round 11
// 135.207 us; speedup vs baseline: 2.3548x; 1.1576x over previous
//
#include <hip/hip_runtime.h>
#include <hip/hip_bf16.h>

typedef short v8s __attribute__((ext_vector_type(8)));
typedef float v4f __attribute__((ext_vector_type(4)));

#define MFMA16(a, b, c) __builtin_amdgcn_mfma_f32_16x16x32_bf16((a), (b), (c), 0, 0, 0)

typedef __attribute__((address_space(1))) const void g_void;
typedef __attribute__((address_space(3))) void lds_void;
#define GLOAD_LDS16(g, l) \
    __builtin_amdgcn_global_load_lds((g_void*)(g), (lds_void*)(l), 16, 0, 0)

constexpr int Bsz   = 128;
constexpr int Lq    = 32;
constexpr int Ld    = 512;
constexpr int H     = 768;
constexpr int D     = 128;
constexpr int QROWS = Bsz * Lq;          // 4096
constexpr int DROWS = Bsz * Ld;          // 65536
constexpr int MTOT  = QROWS + 2 * DROWS; // 135168
constexpr int BM    = 64;                // rows per block
constexpr int BK    = 64;                // K per tile
constexpr int NT    = H / BK;            // 12 K-tiles
static_assert(QROWS % BM == 0 && DROWS % BM == 0, "block never spans sources");

// f32 -> bf16 bits, round-to-nearest-even
static __device__ __forceinline__ unsigned short f2b(float f) {
    unsigned int u = __builtin_bit_cast(unsigned int, f);
    unsigned int r = u + 0x7FFFu + ((u >> 16) & 1u);
    return (unsigned short)(r >> 16);
}
static __device__ __forceinline__ v8s mk8(float4 f0, float4 f1) {
    v8s a;
    a[0] = (short)f2b(f0.x); a[1] = (short)f2b(f0.y);
    a[2] = (short)f2b(f0.z); a[3] = (short)f2b(f0.w);
    a[4] = (short)f2b(f1.x); a[5] = (short)f2b(f1.y);
    a[6] = (short)f2b(f1.z); a[7] = (short)f2b(f1.w);
    return a;
}

// ---------------------------------------------------------------------------
// Kernel 1: Wt[d][h] = bf16(W[h][d])
// ---------------------------------------------------------------------------
__global__ void prep_w_kernel(const float* __restrict__ W,
                              unsigned short* __restrict__ Wt) {
    int idx = blockIdx.x * 256 + threadIdx.x;
    if (idx < H * D) {
        int d = idx / H, h = idx % H;
        Wt[idx] = f2b(W[h * D + d]);
    }
}

// ---------------------------------------------------------------------------
// Kernel 2: projection. BOTH A and W staged via global_load_lds — the K-loop
// has ZERO register global loads, so the compiler cannot JIT-sink anything
// into the vmcnt FIFO (R6/R9 failure mode). 256 thr = 4 waves (2 mg x 2 ng);
// wave computes 32 rows x 64 cols. A tile [64][64] f32 (16 KB) + W tile
// [128][64] bf16 (16 KB), double-buffered. Per wave per stage = 8 DMA instrs.
// Iter: compute(t) -> lgkmcnt(0)+barrier -> issue S(t+2) -> vmcnt(8)
// (S(t+1) done, S(t+2) in flight; never 0 mid-loop) -> barrier.
// XOR swizzle both sides (rule 21): A chunk16 ^= row&15, W chunk16 ^= d&7.
// ---------------------------------------------------------------------------
__global__ __launch_bounds__(256, 2) void proj_norm_kernel(
    const float* __restrict__ qh, const float* __restrict__ pdh,
    const float* __restrict__ ndh, const float* __restrict__ bias,
    const int* __restrict__ pdm, const int* __restrict__ ndm,
    const unsigned short* __restrict__ Wt, unsigned short* __restrict__ emb)
{
    __shared__ float          Abuf[2][BM * BK];   // 2 x 16 KB
    __shared__ unsigned short Wbuf[2][D * BK];    // 2 x 16 KB
    __shared__ float          ssred[2][BM];

    const int tid  = threadIdx.x;
    const int lane = tid & 63, wave = tid >> 6;
    const int l15  = lane & 15, lg = lane >> 4;
    const int mg   = wave >> 1;                   // row half (32 rows)
    const int ng   = wave & 1;                    // col half (64 cols)
    const long row0 = (long)blockIdx.x * BM;

    const float* src; const int* mask; long srow;
    if (row0 < QROWS)              { src = qh;  srow = row0;                 mask = nullptr; }
    else if (row0 < QROWS + DROWS) { src = pdh; srow = row0 - QROWS;         mask = pdm; }
    else                           { src = ndh; srow = row0 - QROWS - DROWS; mask = ndm; }

    // ---- staging (per wave: 4 A instrs + 4 W instrs per tile) ----
    // A instr i: rows 16w+4i..+3. lane l -> row +(l>>4), phys slot l&15 holds
    // logical chunk (l&15)^(row&15). 1 KB contiguous LDS per instr.
    auto stageA = [&](int bi, int kt) {
#pragma unroll
        for (int i = 0; i < 4; ++i) {
            const int row = 16 * wave + 4 * i + (lane >> 4);
            const int cs  = (lane & 15) ^ (row & 15);
            const float* gp = src + (srow + row) * (long)H + kt * BK + cs * 4;
            GLOAD_LDS16(gp, &Abuf[bi][(16 * wave + 4 * i) * BK]);
        }
    };
    // W instr i: d-rows 32w+8i..+7. lane l -> d +(l>>3), phys slot l&7 holds
    // logical chunk (l&7)^(d&7) (d&7 == l>>3 here).
    auto stageW = [&](int bi, int kt) {
#pragma unroll
        for (int i = 0; i < 4; ++i) {
            const int d  = 32 * wave + 8 * i + (lane >> 3);
            const int cw = (lane & 7) ^ (lane >> 3);
            const unsigned short* gp = Wt + (size_t)d * H + kt * BK + cw * 8;
            GLOAD_LDS16(gp, &Wbuf[bi][(32 * wave + 8 * i) * BK]);
        }
    };

    v4f acc[2][4];
#pragma unroll
    for (int mt = 0; mt < 2; ++mt)
#pragma unroll
        for (int nt = 0; nt < 4; ++nt) acc[mt][nt] = (v4f){0.f, 0.f, 0.f, 0.f};

    auto compute = [&](int bi) {
#pragma unroll
        for (int kk = 0; kk < 2; ++kk) {
            v8s wfr[4];
#pragma unroll
            for (int nt = 0; nt < 4; ++nt) {
                const int d  = ng * 64 + nt * 16 + l15;
                const int ch = (kk * 4 + lg) ^ (l15 & 7);
                wfr[nt] = *(const v8s*)(&Wbuf[bi][d * BK + ch * 8]);
            }
#pragma unroll
            for (int mt = 0; mt < 2; ++mt) {
                const int r  = mg * 32 + mt * 16 + l15;
                const int j0 = (kk * 8 + lg * 2)     ^ l15;
                const int j1 = (kk * 8 + lg * 2 + 1) ^ l15;
                const float* rp = &Abuf[bi][r * BK];
                float4 f0 = *(const float4*)(rp + j0 * 4);
                float4 f1 = *(const float4*)(rp + j1 * 4);
                v8s a = mk8(f0, f1);
#pragma unroll
                for (int nt = 0; nt < 4; ++nt)
                    acc[mt][nt] = MFMA16(a, wfr[nt], acc[mt][nt]);
            }
        }
    };

    // prologue: S(0), S(1) in flight; complete S(0)
    stageA(0, 0); stageW(0, 0);
    stageA(1, 1); stageW(1, 1);
    asm volatile("s_waitcnt vmcnt(8)" ::: "memory");
    __builtin_amdgcn_sched_barrier(0);
    __builtin_amdgcn_s_barrier();

#pragma unroll
    for (int t = 0; t < NT; ++t) {
        compute(t & 1);
        // all my ds_reads of buf(t) fully complete before signaling
        asm volatile("s_waitcnt lgkmcnt(0)" ::: "memory");
        __builtin_amdgcn_sched_barrier(0);
        __builtin_amdgcn_s_barrier();          // buf(t) free for S(t+2)
        if (t + 2 < NT) { stageA(t & 1, t + 2); stageW(t & 1, t + 2); }
        if (t + 1 < NT) {
            if (t + 2 < NT) {
                asm volatile("s_waitcnt vmcnt(8)" ::: "memory"); // S(t+1) done
            } else {
                asm volatile("s_waitcnt vmcnt(0)" ::: "memory"); // tail drain
            }
            __builtin_amdgcn_sched_barrier(0);
            __builtin_amdgcn_s_barrier();      // S(t+1) visible to all waves
        }
    }

    // ---- epilogue: bias, cross-ng L2-norm, mask, store bf16 ----
    float bv[4];
#pragma unroll
    for (int nt = 0; nt < 4; ++nt) bv[nt] = bias[ng * 64 + nt * 16 + l15];

    float ss[2][4];
#pragma unroll
    for (int mt = 0; mt < 2; ++mt)
#pragma unroll
        for (int q = 0; q < 4; ++q) {
            float s = 0.f;
#pragma unroll
            for (int nt = 0; nt < 4; ++nt) {
                float v = acc[mt][nt][q] + bv[nt];
                acc[mt][nt][q] = v;
                s += v * v;
            }
            ss[mt][q] = s;
        }
#pragma unroll
    for (int off = 1; off < 16; off <<= 1)
#pragma unroll
        for (int mt = 0; mt < 2; ++mt)
#pragma unroll
            for (int q = 0; q < 4; ++q)
                ss[mt][q] += __shfl_xor(ss[mt][q], off);

    if (l15 == 0) {
#pragma unroll
        for (int mt = 0; mt < 2; ++mt)
#pragma unroll
            for (int q = 0; q < 4; ++q)
                ssred[ng][mg * 32 + mt * 16 + lg * 4 + q] = ss[mt][q];
    }
    __syncthreads();   // nothing in flight now; full sync is safe

#pragma unroll
    for (int mt = 0; mt < 2; ++mt)
#pragma unroll
        for (int q = 0; q < 4; ++q) {
            const int row = mg * 32 + mt * 16 + lg * 4 + q;
            float t = ssred[0][row] + ssred[1][row];
            float s = 1.0f / fmaxf(sqrtf(t), 1e-12f);
            if (mask) s *= (float)mask[srow + row];
            unsigned short* op = emb + (size_t)(row0 + row) * D + ng * 64 + l15;
#pragma unroll
            for (int nt = 0; nt < 4; ++nt)
                op[nt * 16] = f2b(acc[mt][nt][q] * s);
        }
}

// ---------------------------------------------------------------------------
// Kernel 3: MaxSim. One block per (batch, side); 4 waves x 128 doc tokens.
// ---------------------------------------------------------------------------
__global__ __launch_bounds__(256) void maxsim_kernel(
    const unsigned short* __restrict__ emb, float* __restrict__ out)
{
    const int blk  = blockIdx.x;       // 0..255
    const int b    = blk >> 1, side = blk & 1;
    const int wave = threadIdx.x >> 6, lane = threadIdx.x & 63;
    const int l15  = lane & 15, lg = lane >> 4;

    const unsigned short* Q  = emb + (size_t)(b * Lq) * D;
    const unsigned short* Dm = emb + (size_t)(QROWS + side * DROWS + b * Ld) * D;

    v4f acc[2][8];
#pragma unroll
    for (int m = 0; m < 2; ++m)
#pragma unroll
        for (int n = 0; n < 8; ++n) acc[m][n] = (v4f){0.f, 0.f, 0.f, 0.f};

    const int tok0 = wave * 128;
#pragma unroll
    for (int kk = 0; kk < 4; ++kk) {
        const int k0 = kk * 32 + lg * 8;
        v8s qa0 = *(const v8s*)(Q + (size_t)(l15) * D + k0);
        v8s qa1 = *(const v8s*)(Q + (size_t)(16 + l15) * D + k0);
#pragma unroll
        for (int n = 0; n < 8; ++n) {
            v8s db = *(const v8s*)(Dm + (size_t)(tok0 + n * 16 + l15) * D + k0);
            acc[0][n] = MFMA16(qa0, db, acc[0][n]);
            acc[1][n] = MFMA16(qa1, db, acc[1][n]);
        }
    }

    float mx[2][4];
#pragma unroll
    for (int m = 0; m < 2; ++m)
#pragma unroll
        for (int r = 0; r < 4; ++r) {
            float v = acc[m][0][r];
#pragma unroll
            for (int n = 1; n < 8; ++n) v = fmaxf(v, acc[m][n][r]);
            mx[m][r] = v;
        }
#pragma unroll
    for (int off = 1; off < 16; off <<= 1) {
#pragma unroll
        for (int m = 0; m < 2; ++m)
#pragma unroll
            for (int r = 0; r < 4; ++r)
                mx[m][r] = fmaxf(mx[m][r], __shfl_xor(mx[m][r], off));
    }

    __shared__ float red[4][32];
    if (l15 == 0) {
#pragma unroll
        for (int m = 0; m < 2; ++m)
#pragma unroll
            for (int r = 0; r < 4; ++r)
                red[wave][m * 16 + lg * 4 + r] = mx[m][r];
    }
    __syncthreads();

    if (threadIdx.x < 32) {
        int q = threadIdx.x;
        float v = fmaxf(fmaxf(red[0][q], red[1][q]), fmaxf(red[2][q], red[3][q]));
#pragma unroll
        for (int off = 1; off < 32; off <<= 1) v += __shfl_xor(v, off);
        if (q == 0) out[blk] = v;
    }
}

// ---------------------------------------------------------------------------
extern "C" void kernel_launch(void* const* d_in, const int* in_sizes, int n_in,
                              void* d_out, int out_size, void* d_ws, size_t ws_size,
                              hipStream_t stream)
{
    const float* qh   = (const float*)d_in[0];
    const float* pdh  = (const float*)d_in[1];
    const float* ndh  = (const float*)d_in[2];
    const float* W    = (const float*)d_in[3];
    const float* bias = (const float*)d_in[4];
    const int*   pdm  = (const int*)d_in[5];
    const int*   ndm  = (const int*)d_in[6];
    float* out = (float*)d_out;

    unsigned short* Wt  = (unsigned short*)d_ws;          // [D][H] bf16, 192 KB
    unsigned short* emb = Wt + (size_t)H * D;             // [MTOT][D] bf16

    prep_w_kernel<<<(H * D + 255) / 256, 256, 0, stream>>>(W, Wt);
    proj_norm_kernel<<<MTOT / BM, 256, 0, stream>>>(qh, pdh, ndh, bias, pdm, ndm, Wt, emb);
    maxsim_kernel<<<Bsz * 2, 256, 0, stream>>>(emb, out);
}